// Round 3
// baseline (198.733 us; speedup 1.0000x reference)
//
#include <hip/hip_runtime.h>

typedef short bf16x8 __attribute__((ext_vector_type(8)));   // 8 bf16 in 4 VGPRs
typedef float f32x4  __attribute__((ext_vector_type(4)));
typedef int   i32x4  __attribute__((ext_vector_type(4)));
typedef unsigned int u32x2 __attribute__((ext_vector_type(2)));

#define DEV static __device__ __forceinline__

DEV float bfu_to_f(unsigned short s) { return __builtin_bit_cast(float, (unsigned int)s << 16); }
DEV unsigned short f_to_bf(float f) {                 // RNE fp32 -> bf16
  unsigned int u = __builtin_bit_cast(unsigned int, f);
  u += 0x7fffu + ((u >> 16) & 1u);
  return (unsigned short)(u >> 16);
}

// dtype discriminator: adj[0][0] == 1.0 exactly. fp32 word0 == 0x3F800000.
// bf16 word0 = (adj01<<16)|0x3F80 whose low halfword is 0x3F80 != 0 -> never equal.
DEV bool detect_f32(const void* adj) { return ((const float*)adj)[0] == 1.0f; }

template<bool F32> DEV float ldS(const void* p, size_t i) {
  if constexpr (F32) return ((const float*)p)[i];
  else               return bfu_to_f(((const unsigned short*)p)[i]);
}

// 8 contiguous elements -> float[8]  (call sites: i % 8 == 0, base 16B-aligned)
template<bool F32> DEV void ld8f(const void* p, size_t i, float* o) {
  if constexpr (F32) {
    const float* f = (const float*)p + i;
    f32x4 a = *(const f32x4*)f, b = *(const f32x4*)(f + 4);
    o[0]=a[0]; o[1]=a[1]; o[2]=a[2]; o[3]=a[3];
    o[4]=b[0]; o[5]=b[1]; o[6]=b[2]; o[7]=b[3];
  } else {
    i32x4 w = *(const i32x4*)((const unsigned short*)p + i);
#pragma unroll
    for (int k = 0; k < 4; ++k) {
      unsigned int u = (unsigned int)w[k];
      o[2*k]   = __builtin_bit_cast(float, u << 16);
      o[2*k+1] = __builtin_bit_cast(float, u & 0xffff0000u);
    }
  }
}

// 8 contiguous elements -> bf16x8 MFMA fragment (bf16 path = raw bits, exact)
template<bool F32> DEV bf16x8 ldfrag(const void* p, size_t i) {
  if constexpr (F32) {
    float o[8]; ld8f<true>(p, i, o);
    union { bf16x8 v; unsigned short u[8]; } r;
#pragma unroll
    for (int k = 0; k < 8; ++k) r.u[k] = f_to_bf(o[k]);
    return r.v;
  } else {
    return __builtin_bit_cast(bf16x8, *(const i32x4*)((const unsigned short*)p + i));
  }
}

// ---------------- Kernel 1: h = x @ W^T  -> bf16 ws ----------------
template<bool F32> DEV void k_h_body(const void* __restrict__ x, const void* __restrict__ W,
                                     unsigned short* __restrict__ h) {
  const int lane = threadIdx.x & 63, wave = threadIdx.x >> 6;
  const int tile = blockIdx.x * 4 + wave;      // 8192 tiles
  const int rt = tile >> 3, ct = tile & 7;
  const int m = lane & 15, q = lane >> 4;
  const size_t xo = (size_t)(rt * 16 + m) * 128 + q * 8;
  const size_t wo = (size_t)(ct * 16 + m) * 128 + q * 8;
  f32x4 acc = {0.f, 0.f, 0.f, 0.f};
#pragma unroll
  for (int k = 0; k < 4; ++k)
    acc = __builtin_amdgcn_mfma_f32_16x16x32_bf16(ldfrag<F32>(x, xo + k * 32),
                                                  ldfrag<F32>(W, wo + k * 32), acc, 0, 0, 0);
  unsigned short* hp = h + (size_t)(rt * 16 + q * 4) * 128 + ct * 16 + m;  // C: col=m, row=q*4+r
#pragma unroll
  for (int r = 0; r < 4; ++r) hp[(size_t)r * 128] = f_to_bf(acc[r]);
}
__global__ __launch_bounds__(256) void k_h(const void* x, const void* W,
                                           unsigned short* h, const void* adj) {
  if (detect_f32(adj)) k_h_body<true>(x, W, h); else k_h_body<false>(x, W, h);
}

// ---------------- Kernel 1b: src/dst projections ----------------
template<bool F32> DEV void k_sd_body(const unsigned short* __restrict__ h,
                                      const void* __restrict__ a_src, const void* __restrict__ a_dst,
                                      float* __restrict__ srcv, float* __restrict__ dstv) {
  const int t = blockIdx.x * 256 + threadIdx.x;      // (bh, n), n fastest
  const int n = t & 2047, bh = t >> 11;
  const int b = bh >> 2, hh = bh & 3;
  const size_t hi = ((size_t)b * 2048 + n) * 128 + hh * 32;
  float s = 0.f, d = 0.f;
#pragma unroll
  for (int v = 0; v < 4; ++v) {
    float hv[8], sa[8], da[8];
    ld8f<false>(h, hi + v * 8, hv);
    ld8f<F32>(a_src, (size_t)hh * 32 + v * 8, sa);
    ld8f<F32>(a_dst, (size_t)hh * 32 + v * 8, da);
#pragma unroll
    for (int k = 0; k < 8; ++k) { s += hv[k] * sa[k]; d += hv[k] * da[k]; }
  }
  srcv[t] = s; dstv[t] = d;
}
__global__ __launch_bounds__(256) void k_sd(const unsigned short* h, const void* a_src,
                                            const void* a_dst, float* srcv, float* dstv,
                                            const void* adj) {
  if (detect_f32(adj)) k_sd_body<true>(h, a_src, a_dst, srcv, dstv);
  else                 k_sd_body<false>(h, a_src, a_dst, srcv, dstv);
}

// ---------------- Kernel 2: flash-style GAT attention ----------------
// attn_ij = A_ij * exp(leaky(src_i+dst_j)) / den_i  (A in {0}U[0.5,1]: log/exp/clip cancel)
template<bool F32> DEV void k_attn_body(const void* __restrict__ adj,
                                        const unsigned short* __restrict__ h,
                                        const float* __restrict__ srcv,
                                        const float* __restrict__ dstv,
                                        unsigned short* __restrict__ ao) {
  __shared__ __align__(16) float dst_s[2048];
  __shared__ __align__(16) unsigned short h_t[32][40];   // [d][j], pad to 80B rows
  __shared__ float den_s[64];
  const int tid = threadIdx.x;
  const int lane = tid & 63, wave = tid >> 6;
  const int itile = blockIdx.x & 31, bh = blockIdx.x >> 5;
  const int b = bh >> 2, hh = bh & 3;
  const int m = lane & 15, q = lane >> 4;
  const int i = itile * 64 + wave * 16 + m;

  const float* dstp = dstv + bh * 2048;
  for (int k2 = tid * 4; k2 < 2048; k2 += 1024)
    *(f32x4*)&dst_s[k2] = *(const f32x4*)&dstp[k2];

  const float src_i = srcv[bh * 2048 + i];
  const size_t arow = (size_t)i * 2048 + q * 8;
  const int j_loc = tid >> 3, dg = tid & 7;
  const unsigned short* hstage = h + (size_t)b * 2048 * 128 + hh * 32 + (size_t)j_loc * 128 + dg * 4;

  f32x4 acc0 = {0.f,0.f,0.f,0.f}, acc1 = {0.f,0.f,0.f,0.f};
  float den = 0.f;

  for (int jt = 0; jt < 2048; jt += 32) {
    __syncthreads();                                    // h_t free (covers dst_s on iter 0)
    u32x2 hv = *(const u32x2*)(hstage + (size_t)jt * 128);
    h_t[dg * 4 + 0][j_loc] = (unsigned short)(hv[0] & 0xffffu);
    h_t[dg * 4 + 1][j_loc] = (unsigned short)(hv[0] >> 16);
    h_t[dg * 4 + 2][j_loc] = (unsigned short)(hv[1] & 0xffffu);
    h_t[dg * 4 + 3][j_loc] = (unsigned short)(hv[1] >> 16);
    __syncthreads();

    float av[8]; ld8f<F32>(adj, arow + jt, av);
    union { bf16x8 v; unsigned short u[8]; } pk;
    float dsum = 0.f;
#pragma unroll
    for (int pp = 0; pp < 8; ++pp) {
      float s = src_i + dst_s[jt + q * 8 + pp];
      s = (s > 0.f) ? s : 0.2f * s;
      s = fminf(s, 80.f);                               // guard: no exp overflow even on garbage
      float p = (av[pp] > 0.f) ? av[pp] * __expf(s) : 0.f;
      p = fminf(p, 1e30f);                              // guard: finite
      const unsigned short pb = f_to_bf(p);
      pk.u[pp] = pb;
      dsum += bfu_to_f(pb);                             // den from SAME rounded p as numerator
    }
    den += dsum;
    bf16x8 bf0 = *(const bf16x8*)&h_t[m][q * 8];        // B[k=j][n=d]: d=m, k=q*8+jj
    bf16x8 bf1 = *(const bf16x8*)&h_t[16 + m][q * 8];
    acc0 = __builtin_amdgcn_mfma_f32_16x16x32_bf16(pk.v, bf0, acc0, 0, 0, 0);
    acc1 = __builtin_amdgcn_mfma_f32_16x16x32_bf16(pk.v, bf1, acc1, 0, 0, 0);
  }

  den += __shfl_xor(den, 16, 64);                       // row i lives on lanes m,m+16,m+32,m+48
  den += __shfl_xor(den, 32, 64);
  if (q == 0) den_s[wave * 16 + m] = den;
  __syncthreads();

  unsigned short* op = ao + ((size_t)b * 2048 + itile * 64 + wave * 16 + q * 4) * 128 + hh * 32 + m;
#pragma unroll
  for (int r = 0; r < 4; ++r) {
    const float inv = 1.f / fmaxf(den_s[wave * 16 + q * 4 + r], 1e-20f);  // guard: no div-by-0
    op[(size_t)r * 128]      = f_to_bf(acc0[r] * inv);
    op[(size_t)r * 128 + 16] = f_to_bf(acc1[r] * inv);
  }
}
__global__ __launch_bounds__(256) void k_attn(const void* adj, const unsigned short* h,
                                              const float* srcv, const float* dstv,
                                              unsigned short* ao) {
  if (detect_f32(adj)) k_attn_body<true>(adj, h, srcv, dstv, ao);
  else                 k_attn_body<false>(adj, h, srcv, dstv, ao);
}

// ---------------- Kernel 3: y = LN(ao @ Wo^T + bo + x) ----------------
template<bool F32> DEV void k_out_body(const unsigned short* __restrict__ ao,
                                       const void* __restrict__ Wo, const void* __restrict__ bo,
                                       const void* __restrict__ x, const void* __restrict__ gamma,
                                       const void* __restrict__ beta, void* __restrict__ out) {
  __shared__ __align__(16) float y_s[16][132];
  const int tid = threadIdx.x, lane = tid & 63, wave = tid >> 6;
  const int m = lane & 15, q = lane >> 4;
  const int rbase = blockIdx.x * 16;
  bf16x8 af[4];
#pragma unroll
  for (int k = 0; k < 4; ++k)
    af[k] = ldfrag<false>(ao, ((size_t)(rbase + m)) * 128 + q * 8 + k * 32);
  f32x4 acc[2] = {{0.f,0.f,0.f,0.f},{0.f,0.f,0.f,0.f}};
#pragma unroll
  for (int ct = 0; ct < 2; ++ct) {
    const size_t wrow = (size_t)(wave * 32 + ct * 16 + m) * 128 + q * 8;
#pragma unroll
    for (int k = 0; k < 4; ++k)
      acc[ct] = __builtin_amdgcn_mfma_f32_16x16x32_bf16(af[k], ldfrag<F32>(Wo, wrow + k * 32),
                                                        acc[ct], 0, 0, 0);
  }
#pragma unroll
  for (int ct = 0; ct < 2; ++ct) {
    const int c = wave * 32 + ct * 16 + m;
    const float bov = ldS<F32>(bo, c);
#pragma unroll
    for (int r = 0; r < 4; ++r) {
      const int row = q * 4 + r;
      y_s[row][c] = acc[ct][r] + bov + ldS<F32>(x, (size_t)(rbase + row) * 128 + c);
    }
  }
  __syncthreads();
  const int r = tid >> 4, c16 = tid & 15;
  float vals[8], sum = 0.f, sq = 0.f;
#pragma unroll
  for (int k = 0; k < 8; ++k) {
    const float v = y_s[r][c16 * 8 + k];
    vals[k] = v; sum += v; sq += v * v;
  }
#pragma unroll
  for (int msk = 1; msk < 16; msk <<= 1) {
    sum += __shfl_xor(sum, msk, 16);
    sq  += __shfl_xor(sq,  msk, 16);
  }
  const float mu  = sum * (1.f / 128.f);
  const float var = fmaxf(sq * (1.f / 128.f) - mu * mu, 0.f);
  const float rstd = rsqrtf(var + 1e-5f);
  float o[8];
#pragma unroll
  for (int k = 0; k < 8; ++k) {
    const int c = c16 * 8 + k;
    o[k] = (vals[k] - mu) * rstd * ldS<F32>(gamma, c) + ldS<F32>(beta, c);
  }
  const size_t obase = (size_t)(rbase + r) * 128 + c16 * 8;
  if constexpr (F32) {
    float* op = (float*)out + obase;
    f32x4 w0 = {o[0],o[1],o[2],o[3]}, w1 = {o[4],o[5],o[6],o[7]};
    *(f32x4*)op = w0; *(f32x4*)(op + 4) = w1;
  } else {
    union { unsigned short u[8]; i32x4 v; } ob;
#pragma unroll
    for (int k = 0; k < 8; ++k) ob.u[k] = f_to_bf(o[k]);
    *(i32x4*)((unsigned short*)out + obase) = ob.v;
  }
}
__global__ __launch_bounds__(256) void k_out(const unsigned short* ao, const void* Wo,
                                             const void* bo, const void* x, const void* gamma,
                                             const void* beta, void* out, const void* adj) {
  if (detect_f32(adj)) k_out_body<true>(ao, Wo, bo, x, gamma, beta, out);
  else                 k_out_body<false>(ao, Wo, bo, x, gamma, beta, out);
}

// ---------------- launch ----------------
extern "C" void kernel_launch(void* const* d_in, const int* in_sizes, int n_in,
                              void* d_out, int out_size, void* d_ws, size_t ws_size,
                              hipStream_t stream) {
  const void* x     = d_in[0];
  const void* adj   = d_in[1];
  const void* W     = d_in[2];
  const void* a_src = d_in[3];
  const void* a_dst = d_in[4];
  const void* Wo    = d_in[5];
  const void* bo    = d_in[6];
  const void* gamma = d_in[7];
  const void* beta  = d_in[8];

  unsigned short* h_ws  = (unsigned short*)d_ws;                    // 4 MB bf16 h (B,N,D)
  unsigned short* ao_ws = h_ws + (size_t)8 * 2048 * 128;            // 4 MB bf16 attn out
  float* src_ws = (float*)(ao_ws + (size_t)8 * 2048 * 128);         // 256 KB fp32 (B,H,N)
  float* dst_ws = src_ws + (size_t)8 * 4 * 2048;                    // 256 KB fp32 (B,H,N)

  k_h   <<<2048, 256, 0, stream>>>(x, W, h_ws, adj);
  k_sd  <<<256,  256, 0, stream>>>(h_ws, a_src, a_dst, src_ws, dst_ws, adj);
  k_attn<<<1024, 256, 0, stream>>>(adj, h_ws, src_ws, dst_ws, ao_ws);
  k_out <<<1024, 256, 0, stream>>>(ao_ws, Wo, bo, x, gamma, beta, d_out, adj);
}